// Round 11
// baseline (675.452 us; speedup 1.0000x reference)
//
#include <hip/hip_runtime.h>
#include <math.h>

// Problem constants
#define Bn   8
#define Nn   2048
#define Dn   192
#define Gn   512
#define Sn   32
#define OUTn 384
#define Mrows (Bn * Gn * Sn)   // 131072 rows through the MLP

typedef __attribute__((ext_vector_type(8))) unsigned short ushortx8;
typedef __attribute__((ext_vector_type(8))) __bf16 bf16x8;
typedef __attribute__((ext_vector_type(4))) float floatx4;

// ---------- ws layout (bytes) ----------
static constexpr size_t OFF_KNN   = 0;                    // 131072 * 4
static constexpr size_t OFF_CIDX  = 524288;               // 4096 * 4
static constexpr size_t OFF_DIFF  = 540672;               // 393216 * 4
static constexpr size_t OFF_SUMS  = 2113536;              // 2 doubles
static constexpr size_t OFF_STD   = 2113552;              // 1 float (stores 1/std)
static constexpr size_t OFF_CNT   = 2113568;              // 1 int (knn done counter)
static constexpr size_t OFF_DENOM = 2113792;              // 64 floats (stores 1/denom)
static constexpr size_t OFF_W1B   = 2114048;              // 147456 * 2
static constexpr size_t OFF_WAB   = 2408960;              // 73728 * 2
static constexpr size_t OFF_WBB   = 2556416;              // 73728 * 2
static constexpr size_t OFF_G1    = 2703872;              // 50331648 * 2
static constexpr size_t OFF_FEATB = 103367168;            // 3145728 * 2 (bf16 feats)

__device__ __forceinline__ unsigned short f2bf(float f) {
  unsigned u = __float_as_uint(f);
  unsigned r = (u + 0x7FFFu + ((u >> 16) & 1u)) >> 16;   // RNE
  return (unsigned short)r;
}
__device__ __forceinline__ float bf2f(unsigned short h) {
  return __uint_as_float(((unsigned)h) << 16);
}
__device__ __forceinline__ floatx4 mfma_bf16(ushortx8 a, ushortx8 b, floatx4 c) {
  return __builtin_amdgcn_mfma_f32_16x16x32_bf16(
      __builtin_bit_cast(bf16x8, a), __builtin_bit_cast(bf16x8, b), c, 0, 0, 0);
}

// async global->LDS, 16 B per lane. LDS dest = wave-uniform base + lane*16.
__device__ __forceinline__ void gld16(const void* g, void* l) {
  __builtin_amdgcn_global_load_lds(
      (const __attribute__((address_space(1))) unsigned int*)g,
      (__attribute__((address_space(3))) unsigned int*)l, 16, 0, 0);
}

template <int CTRL>
__device__ __forceinline__ float dpp_max(float v) {
  int o = __builtin_amdgcn_update_dpp(0, __float_as_int(v), CTRL, 0xf, 0xf, true);
  return fmaxf(v, __int_as_float(o));
}

// ---------------------------------------------------------------------------
// FPS + PREP merged (512 threads): blocks 0-7 run FPS with 8 waves, 4 pts/
// lane (halved dist-update chain vs r5's 4-wave/8-pt shape); blocks 8+ do
// the bf16 conversions on otherwise-idle CUs (fully hidden under fps).
// FPS keeps the r5-PROVEN residency pattern: points staged via LDS p4[]
// then filled into registers FROM LDS (LDS source keeps them in VGPRs;
// global source triggers remat/spill — r6/r7 counter evidence). No asm pins.
// Lane-major n = t*4+k -> lowest tied lane == smallest global index; DPP
// wave max + scalar resolve; 8-slot u64 exchange; distance math
// bit-identical to numpy ref (no FMA contraction), first-index ties exact.
// ---------------------------------------------------------------------------
__global__ __launch_bounds__(512) void fps_prep_kernel(
    const float* __restrict__ points, float* __restrict__ centers,
    const float* __restrict__ W1, const float* __restrict__ Wa,
    const float* __restrict__ Wb, const float* __restrict__ feats,
    unsigned short* __restrict__ W1b, unsigned short* __restrict__ Wab,
    unsigned short* __restrict__ Wbb, unsigned short* __restrict__ featb,
    float* __restrict__ rdenomTab) {
  const int t = threadIdx.x;

  if (blockIdx.x >= 8) {
    // ---- prep path: 2048 elems/block ----
    const int base = (blockIdx.x - 8) * 2048 + t;
#pragma unroll
    for (int j = 0; j < 4; ++j) {
      const int i = base + j * 512;    // < 3440640 by grid construction
      if (i < 147456)        W1b[i] = f2bf(W1[i]);
      else if (i < 221184)   Wab[i - 147456] = f2bf(Wa[i - 147456]);
      else if (i < 294912)   Wbb[i - 221184] = f2bf(Wb[i - 221184]);
      else                   featb[i - 294912] = f2bf(feats[i - 294912]);
    }
    if (blockIdx.x == 8 && t < 64)
      rdenomTab[t] = (float)(1.0 / pow(1000.0, (double)t / 64.0));
    return;
  }

  // ---- fps path: 8 waves, 4 pts/lane ----
  const int b = blockIdx.x;
  const int w = t >> 6, lane = t & 63;
  __shared__ float4 p4[Nn];
  __shared__ unsigned long long wkey[2][8];

  const float* P = points + (size_t)b * Nn * 3;
  for (int n = t; n < Nn; n += 512) {
    float x = P[n * 3], y = P[n * 3 + 1], z = P[n * 3 + 2];
    p4[n] = make_float4(x, y, z, 0.f);
  }
  __syncthreads();

  float rx[4], ry[4], rz[4], dist[4];
#pragma unroll
  for (int k = 0; k < 4; ++k) {
    float4 p = p4[t * 4 + k];       // LDS source -> stays in VGPRs (r5/r9)
    rx[k] = p.x; ry[k] = p.y; rz[k] = p.z;
    dist[k] = INFINITY;
  }

  int cur = 0;
  for (int it = 0; it < Gn; ++it) {
    const float4 c = p4[cur];
    if (t == 0) {
      float* cd = centers + ((size_t)b * Gn + it) * 3;
      cd[0] = c.x; cd[1] = c.y; cd[2] = c.z;
    }
    float bv = -1.0f;
#pragma unroll
    for (int k = 0; k < 4; ++k) {
      float dx = __fsub_rn(rx[k], c.x);
      float dy = __fsub_rn(ry[k], c.y);
      float dz = __fsub_rn(rz[k], c.z);
      float d = __fadd_rn(__fadd_rn(__fmul_rn(dx, dx), __fmul_rn(dy, dy)), __fmul_rn(dz, dz));
      dist[k] = fminf(dist[k], d);
      bv = fmaxf(bv, dist[k]);
    }
    int li = 3;
#pragma unroll
    for (int k = 2; k >= 0; --k) li = (dist[k] == bv) ? k : li;

    float red = bv;
    red = dpp_max<0x111>(red);   // row_shr:1
    red = dpp_max<0x112>(red);   // row_shr:2
    red = dpp_max<0x114>(red);   // row_shr:4
    red = dpp_max<0x118>(red);   // row_shr:8
    red = dpp_max<0x142>(red);   // row_bcast:15
    red = dpp_max<0x143>(red);   // row_bcast:31
    const float M = __int_as_float(__builtin_amdgcn_readlane(__float_as_int(red), 63));

    unsigned long long msk = __ballot(bv == M);
    const int L = __ffsll((long long)msk) - 1;
    const int liL = __builtin_amdgcn_readlane(li, L);
    const int idx = (w * 64 + L) * 4 + liL;

    unsigned long long key =
        ((unsigned long long)__float_as_uint(M) << 32) | (unsigned)(0x7FFFFFFF - idx);
    const int buf = it & 1;
    if (lane == 0) wkey[buf][w] = key;
    __syncthreads();
    unsigned long long kk[8];
#pragma unroll
    for (int i = 0; i < 8; ++i) kk[i] = wkey[buf][i];
#pragma unroll
    for (int stride = 1; stride < 8; stride <<= 1)
#pragma unroll
      for (int i = 0; i < 8; i += 2 * stride)
        kk[i] = (kk[i + stride] > kk[i]) ? kk[i + stride] : kk[i];
    cur = 0x7FFFFFFF - (int)(unsigned)kk[0];
  }
}

// ---------------------------------------------------------------------------
// KNN (wave-per-group, no LDS in hot path) + fused stddev: the last block to
// finish computes 1/(std+eps) (device-scope atomics + fences per G12/G16).
// ---------------------------------------------------------------------------
__global__ __launch_bounds__(256) void knn_kernel(const float* __restrict__ points,
                                                  const float* __restrict__ centers,
                                                  int* __restrict__ knn, int* __restrict__ cidx,
                                                  float* __restrict__ diffb,
                                                  double* __restrict__ sums,
                                                  int* __restrict__ cnt,
                                                  float* __restrict__ stdp) {
  const int t = threadIdx.x;
  const int w = t >> 6, lane = t & 63;
  const int bg = blockIdx.x * 4 + w;
  const int b = bg >> 9;

  const float* P = points + (size_t)b * Nn * 3;
  const float* cc = centers + (size_t)bg * 3;
  const float cx = cc[0], cy = cc[1], cz = cc[2];
  const float aa = __fadd_rn(__fadd_rn(__fmul_rn(cx, cx), __fmul_rn(cy, cy)), __fmul_rn(cz, cz));

  unsigned key[32];
#pragma unroll 8
  for (int s = 0; s < 32; ++s) {
    const int n = s * 64 + lane;
    float X = P[n * 3], Y = P[n * 3 + 1], Z = P[n * 3 + 2];
    float bbv = __fadd_rn(__fadd_rn(__fmul_rn(X, X), __fmul_rn(Y, Y)), __fmul_rn(Z, Z));
    float dot = __fadd_rn(__fadd_rn(__fmul_rn(cx, X), __fmul_rn(cy, Y)), __fmul_rn(cz, Z));
    float d2 = __fsub_rn(__fadd_rn(aa, bbv), __fmul_rn(2.0f, dot));
    unsigned u = __float_as_uint(d2);
    key[s] = u ^ ((unsigned)((int)u >> 31) | 0x80000000u);
  }

  unsigned mk = key[0]; int ms = 0;
#pragma unroll
  for (int s = 1; s < 32; ++s)
    if (key[s] < mk) { mk = key[s]; ms = s; }

  int mysel = 0;
  for (int it = 0; it < Sn; ++it) {
    unsigned long long p = ((unsigned long long)mk << 32) | (unsigned)(ms * 64 + lane);
#pragma unroll
    for (int off = 1; off <= 32; off <<= 1) {
      unsigned long long o = __shfl_xor(p, off, 64);
      p = (o < p) ? o : p;
    }
    const int n_win = (int)(unsigned)p;
    if (lane == it) mysel = n_win;
    if (lane == (n_win & 63)) {
      const int sw = n_win >> 6;
#pragma unroll
      for (int s = 0; s < 32; ++s)
        if (s == sw) key[s] = 0xFFFFFFFFu;
      mk = key[0]; ms = 0;
#pragma unroll
      for (int s = 1; s < 32; ++s)
        if (key[s] < mk) { mk = key[s]; ms = s; }
    }
  }

  double s1 = 0.0, s2 = 0.0;
  if (lane < Sn) {
    knn[(size_t)bg * Sn + lane] = mysel;
    float X = P[mysel * 3], Y = P[mysel * 3 + 1], Z = P[mysel * 3 + 2];
    float dx = __fsub_rn(X, cx), dy = __fsub_rn(Y, cy), dz = __fsub_rn(Z, cz);
    float* db = diffb + (size_t)bg * 96 + lane * 3;
    db[0] = dx; db[1] = dy; db[2] = dz;
    s1 = (double)dx + (double)dy + (double)dz;
    s2 = (double)dx * (double)dx + (double)dy * (double)dy + (double)dz * (double)dz;
  }
#pragma unroll
  for (int off = 1; off <= 32; off <<= 1) {
    s1 += __shfl_xor(s1, off, 64);
    s2 += __shfl_xor(s2, off, 64);
  }
  if (lane == 0) {
    cidx[bg] = __shfl(mysel, 0, 64);
    atomicAdd(sums, s1);
    atomicAdd(sums + 1, s2);
  }
  __threadfence();
  __syncthreads();
  if (t == 0) {
    const int old = atomicAdd(cnt, 1);
    if (old == (Bn * Gn / 4) - 1) {        // last block: compute 1/(std+eps)
      __threadfence();
      const double S1 = atomicAdd(sums, 0.0);
      const double S2 = atomicAdd(sums + 1, 0.0);
      const double n = (double)(Bn * Gn * Sn * 3);
      const double mean = S1 / n;
      const double var = (S2 - S1 * mean) / (n - 1.0);
      const float stdf = (float)sqrt(var) + 1e-5f;
      *stdp = (float)(1.0 / (double)stdf);
    }
  }
}

// ===========================================================================
// GEMM1 (unchanged, r8/r9-proven): gathered [neighbor|center] feats @ W1^T
// + b1, ReLU, fused Fourier pos-embed -> G1 bf16. 128x128 tile, BK=64, gld16.
// ===========================================================================
__global__ __launch_bounds__(256) void gemm1_kernel(
    const unsigned short* __restrict__ featb, const unsigned short* __restrict__ W1b,
    const float* __restrict__ b1, const int* __restrict__ knn,
    const int* __restrict__ cidx, const float* __restrict__ diffb,
    const float* __restrict__ rstd_p, const float* __restrict__ rdenomTab,
    unsigned short* __restrict__ G1) {
  __shared__ unsigned short As[128 * 64];
  __shared__ unsigned short Bs[128 * 64];
  const int t = threadIdx.x;
  const int bm = blockIdx.x, bn = blockIdx.y;
  const int wid = t >> 6, lane = t & 63, quad = lane >> 4, c16 = lane & 15;
  const int wr = wid >> 1, wc = wid & 1;

  int aOffN[4], aOffC[4], bOff[4];
#pragma unroll
  for (int i = 0; i < 4; ++i) {
    const int slot = i * 256 + t;
    const int row = slot >> 3, segV = slot & 7;
    const int seg = segV ^ (row & 7);
    const int grow = bm * 128 + row;
    const int bg = grow >> 5, s = grow & 31, bb_ = bg >> 9;
    const int nidx = knn[(size_t)bg * Sn + s];
    const int ci = cidx[bg];
    aOffN[i] = (bb_ * Nn + nidx) * Dn + seg * 8;
    aOffC[i] = (bb_ * Nn + ci) * Dn + seg * 8;
    bOff[i] = (bn * 128 + row) * 384 + seg * 8;
  }

  floatx4 acc[4][4];
#pragma unroll
  for (int i = 0; i < 4; ++i)
#pragma unroll
    for (int j = 0; j < 4; ++j) acc[i][j] = (floatx4){0.f, 0.f, 0.f, 0.f};

  for (int kt = 0; kt < 6; ++kt) {
    const int kb = kt * 64;
#pragma unroll
    for (int i = 0; i < 4; ++i) {
      const unsigned short* srcA =
          (kt < 3) ? (featb + aOffN[i] + kb) : (featb + aOffC[i] + (kb - 192));
      gld16(srcA, &As[(i * 256 + wid * 64) * 8]);
      gld16(W1b + bOff[i] + kb, &Bs[(i * 256 + wid * 64) * 8]);
    }
    __syncthreads();
#pragma unroll
    for (int ks = 0; ks < 2; ++ks) {
      ushortx8 af[4], bf[4];
#pragma unroll
      for (int mt = 0; mt < 4; ++mt) {
        const int row = wr * 64 + mt * 16 + c16;
        const int seg = (ks * 4 + quad) ^ (row & 7);
        af[mt] = *(const ushortx8*)&As[row * 64 + seg * 8];
      }
#pragma unroll
      for (int nt = 0; nt < 4; ++nt) {
        const int row = wc * 64 + nt * 16 + c16;
        const int seg = (ks * 4 + quad) ^ (row & 7);
        bf[nt] = *(const ushortx8*)&Bs[row * 64 + seg * 8];
      }
#pragma unroll
      for (int mt = 0; mt < 4; ++mt)
#pragma unroll
        for (int nt = 0; nt < 4; ++nt)
          acc[mt][nt] = mfma_bf16(af[mt], bf[nt], acc[mt][nt]);
    }
    __syncthreads();
  }

  const float rstd = *rstd_p;
  float bias[4], rdnm[4];
  bool usin[4];
#pragma unroll
  for (int nt = 0; nt < 4; ++nt) {
    const int col = bn * 128 + wc * 64 + nt * 16 + c16;
    bias[nt] = b1[col];
    const int j = col & 127;
    usin[nt] = (j < 64);
    rdnm[nt] = rdenomTab[j & 63];
  }
#pragma unroll
  for (int mt = 0; mt < 4; ++mt) {
#pragma unroll
    for (int r = 0; r < 4; ++r) {
      const int row = bm * 128 + wr * 64 + mt * 16 + quad * 4 + r;
      const float dv = diffb[(size_t)row * 3 + bn];     // i3 == bn for 128-col blocks
      const float x = __fmul_rn(dv, rstd);
      const float zb = __fmul_rn(100.0f, x);
#pragma unroll
      for (int nt = 0; nt < 4; ++nt) {
        const int col = bn * 128 + wc * 64 + nt * 16 + c16;
        float y = fmaxf(acc[mt][nt][r] + bias[nt], 0.f);
        float z = __fmul_rn(zb, rdnm[nt]);
        float p = usin[nt] ? __sinf(z) : __cosf(z);
        float g = (y + p) * p;
        G1[(size_t)row * 384 + col] = f2bf(g);
      }
    }
  }
}

// ===========================================================================
// GEMM23 (fused residual block) — r9-measured version: 512 threads (8 waves,
// 2x4), 128 rows/block, 100KB LDS. Phase A: Htile[128][192] = relu(G1@Wa^T
// +ba) -> LDS bf16 (stride 200). Phase B: out = relu(Htile@Wb^T+bb+G1) +
// fused max+mean pool -> d_out. (r10's 64-row variant regressed: doubled
// B-matrix re-staging; reverted.)
// ===========================================================================
__global__ __launch_bounds__(512) void gemm23_kernel(
    const unsigned short* __restrict__ G1, const unsigned short* __restrict__ Wab,
    const float* __restrict__ ba, const unsigned short* __restrict__ Wbb,
    const float* __restrict__ bb, float* __restrict__ outp) {
  __shared__ __align__(16) char smem[100352];
  unsigned short* Htile = (unsigned short*)smem;                  // 128 x 200
  unsigned short* As    = (unsigned short*)(smem + 51200);        // 128 x 64
  unsigned short* BsA   = (unsigned short*)(smem + 51200 + 16384);// 192 x 64
  unsigned short* BsB   = (unsigned short*)(smem + 51200);        // 384 x 64 (aliases As/BsA)

  const int t = threadIdx.x;
  const int bm = blockIdx.x;
  const int lane = t & 63, quad = lane >> 4, c16 = lane & 15;
  const int wid = t >> 6;
  const int wr = wid >> 2, wc = wid & 3;    // 2 x 4 wave grid

  // ---------------- Phase A: Htile = relu(G1 @ Wa^T + ba), K=384 ----------
  int aOff[2], bOffA[3];
#pragma unroll
  for (int i = 0; i < 2; ++i) {
    const int slot = i * 512 + t;
    const int row = slot >> 3, segV = slot & 7;
    aOff[i] = (bm * 128 + row) * 384 + (segV ^ (row & 7)) * 8;
  }
#pragma unroll
  for (int i = 0; i < 3; ++i) {
    const int slot = i * 512 + t;
    const int row = slot >> 3, segV = slot & 7;
    bOffA[i] = row * 384 + (segV ^ (row & 7)) * 8;
  }

  floatx4 accA[4][3];
#pragma unroll
  for (int i = 0; i < 4; ++i)
#pragma unroll
    for (int j = 0; j < 3; ++j) accA[i][j] = (floatx4){0.f, 0.f, 0.f, 0.f};

  for (int kt = 0; kt < 6; ++kt) {
    const int kb = kt * 64;
#pragma unroll
    for (int i = 0; i < 2; ++i) gld16(G1 + aOff[i] + kb, As + ((size_t)(i * 512 + t)) * 8);
#pragma unroll
    for (int i = 0; i < 3; ++i) gld16(Wab + bOffA[i] + kb, BsA + ((size_t)(i * 512 + t)) * 8);
    __syncthreads();
#pragma unroll
    for (int ks = 0; ks < 2; ++ks) {
      ushortx8 af[4], bf[3];
#pragma unroll
      for (int mt = 0; mt < 4; ++mt) {
        const int row = wr * 64 + mt * 16 + c16;
        const int seg = (ks * 4 + quad) ^ (row & 7);
        af[mt] = *(const ushortx8*)&As[row * 64 + seg * 8];
      }
#pragma unroll
      for (int nt = 0; nt < 3; ++nt) {
        const int row = wc * 48 + nt * 16 + c16;       // < 192
        const int seg = (ks * 4 + quad) ^ (row & 7);
        bf[nt] = *(const ushortx8*)&BsA[row * 64 + seg * 8];
      }
#pragma unroll
      for (int mt = 0; mt < 4; ++mt)
#pragma unroll
        for (int nt = 0; nt < 3; ++nt)
          accA[mt][nt] = mfma_bf16(af[mt], bf[nt], accA[mt][nt]);
    }
    __syncthreads();
  }

  // write H tile to LDS (bf16 — same rounding as the old global round-trip)
#pragma unroll
  for (int nt = 0; nt < 3; ++nt) {
    const int col = wc * 48 + nt * 16 + c16;
    const float bias = ba[col];
#pragma unroll
    for (int mt = 0; mt < 4; ++mt)
#pragma unroll
      for (int r = 0; r < 4; ++r) {
        const int row = wr * 64 + mt * 16 + quad * 4 + r;
        Htile[row * 200 + col] = f2bf(fmaxf(accA[mt][nt][r] + bias, 0.f));
      }
  }
  __syncthreads();

  // ---------------- Phase B: out = relu(Htile @ Wb^T + bb + G1) + pool ----
  int bOffB[6];
#pragma unroll
  for (int i = 0; i < 6; ++i) {
    const int slot = i * 512 + t;
    const int row = slot >> 3, segV = slot & 7;
    bOffB[i] = row * 192 + (segV ^ (row & 7)) * 8;
  }

  floatx4 acc[4][6];
#pragma unroll
  for (int i = 0; i < 4; ++i)
#pragma unroll
    for (int j = 0; j < 6; ++j) acc[i][j] = (floatx4){0.f, 0.f, 0.f, 0.f};

  for (int kt = 0; kt < 3; ++kt) {
    const int kb = kt * 64;
#pragma unroll
    for (int i = 0; i < 6; ++i) gld16(Wbb + bOffB[i] + kb, BsB + ((size_t)(i * 512 + t)) * 8);
    __syncthreads();
#pragma unroll
    for (int ks = 0; ks < 2; ++ks) {
      ushortx8 af[4], bf[6];
#pragma unroll
      for (int mt = 0; mt < 4; ++mt) {
        const int row = wr * 64 + mt * 16 + c16;
        af[mt] = *(const ushortx8*)&Htile[row * 200 + kb + ks * 32 + quad * 8];
      }
#pragma unroll
      for (int nt = 0; nt < 6; ++nt) {
        const int row = wc * 96 + nt * 16 + c16;       // < 384
        const int seg = (ks * 4 + quad) ^ (row & 7);
        bf[nt] = *(const ushortx8*)&BsB[row * 64 + seg * 8];
      }
#pragma unroll
      for (int mt = 0; mt < 4; ++mt)
#pragma unroll
        for (int nt = 0; nt < 6; ++nt)
          acc[mt][nt] = mfma_bf16(af[mt], bf[nt], acc[mt][nt]);
    }
    __syncthreads();
  }

#pragma unroll
  for (int nt = 0; nt < 6; ++nt) {
    const int col = wc * 96 + nt * 16 + c16;
    const float bias = bb[col];
    float gmax[2] = {-INFINITY, -INFINITY};
    float gsum[2] = {0.f, 0.f};
#pragma unroll
    for (int mt = 0; mt < 4; ++mt) {
      const int grp = mt >> 1;
#pragma unroll
      for (int r = 0; r < 4; ++r) {
        const int row = bm * 128 + wr * 64 + mt * 16 + quad * 4 + r;
        float v = acc[mt][nt][r] + bias + bf2f(G1[(size_t)row * 384 + col]);
        v = fmaxf(v, 0.f);
        gmax[grp] = fmaxf(gmax[grp], v);
        gsum[grp] += v;
      }
    }
#pragma unroll
    for (int grp = 0; grp < 2; ++grp) {
      float m = gmax[grp], su = gsum[grp];
#pragma unroll
      for (int off = 16; off <= 32; off <<= 1) {
        m = fmaxf(m, __shfl_xor(m, off, 64));
        su += __shfl_xor(su, off, 64);
      }
      if (quad == 0) {
        const int bg = bm * 4 + wr * 2 + grp;
        outp[(size_t)bg * 384 + col] = m + su / 32.0f;
      }
    }
  }
}

// ---------------------------------------------------------------------------
extern "C" void kernel_launch(void* const* d_in, const int* in_sizes, int n_in,
                              void* d_out, int out_size, void* d_ws, size_t ws_size,
                              hipStream_t stream) {
  const float* points = (const float*)d_in[0];
  const float* feats  = (const float*)d_in[1];
  const float* W1 = (const float*)d_in[2];
  const float* b1 = (const float*)d_in[3];
  const float* Wa = (const float*)d_in[4];
  const float* ba = (const float*)d_in[5];
  const float* Wb = (const float*)d_in[6];
  const float* bb = (const float*)d_in[7];
  float* outF = (float*)d_out;

  char* ws = (char*)d_ws;
  int*            knn      = (int*)(ws + OFF_KNN);
  int*            cidx     = (int*)(ws + OFF_CIDX);
  float*          diffb    = (float*)(ws + OFF_DIFF);
  double*         sums     = (double*)(ws + OFF_SUMS);
  float*          stdp     = (float*)(ws + OFF_STD);
  int*            cnt      = (int*)(ws + OFF_CNT);
  float*          rdenomTab= (float*)(ws + OFF_DENOM);
  unsigned short* W1b      = (unsigned short*)(ws + OFF_W1B);
  unsigned short* Wab      = (unsigned short*)(ws + OFF_WAB);
  unsigned short* Wbb      = (unsigned short*)(ws + OFF_WBB);
  unsigned short* G1       = (unsigned short*)(ws + OFF_G1);
  unsigned short* featb    = (unsigned short*)(ws + OFF_FEATB);

  // zero sums(16B) + stdp(4B, rewritten by knn) + cnt(4B) in one memset
  hipMemsetAsync(ws + OFF_SUMS, 0, 40, stream);
  fps_prep_kernel<<<8 + 1680, 512, 0, stream>>>(points, outF, W1, Wa, Wb, feats,
                                                W1b, Wab, Wbb, featb, rdenomTab);
  knn_kernel<<<Bn * Gn / 4, 256, 0, stream>>>(points, outF, knn, cidx, diffb,
                                              sums, cnt, stdp);
  gemm1_kernel<<<dim3(Mrows / 128, 3), 256, 0, stream>>>(featb, W1b, b1, knn, cidx,
                                                         diffb, stdp, rdenomTab, G1);
  gemm23_kernel<<<Mrows / 128, 512, 0, stream>>>(G1, Wab, ba, Wbb, bb, outF + Bn * Gn * 3);
}

// Round 12
// 578.391 us; speedup vs baseline: 1.1678x; 1.1678x over previous
//
#include <hip/hip_runtime.h>
#include <math.h>

// Problem constants
#define Bn   8
#define Nn   2048
#define Dn   192
#define Gn   512
#define Sn   32
#define OUTn 384
#define Mrows (Bn * Gn * Sn)   // 131072 rows through the MLP

typedef __attribute__((ext_vector_type(8))) unsigned short ushortx8;
typedef __attribute__((ext_vector_type(8))) __bf16 bf16x8;
typedef __attribute__((ext_vector_type(4))) float floatx4;

// ---------- ws layout (bytes) ----------
static constexpr size_t OFF_KNN   = 0;                    // 131072 * 4
static constexpr size_t OFF_CIDX  = 524288;               // 4096 * 4
static constexpr size_t OFF_DIFF  = 540672;               // 393216 * 4
static constexpr size_t OFF_SUMS  = 2113536;              // 2 doubles
static constexpr size_t OFF_STD   = 2113552;              // 1 float (stores 1/std)
static constexpr size_t OFF_CNT   = 2113568;              // 1 int (knn done counter)
static constexpr size_t OFF_DENOM = 2113792;              // 64 floats (stores 1/denom)
static constexpr size_t OFF_W1B   = 2114048;              // 147456 * 2
static constexpr size_t OFF_WAB   = 2408960;              // 73728 * 2
static constexpr size_t OFF_WBB   = 2556416;              // 73728 * 2
static constexpr size_t OFF_G1    = 2703872;              // 50331648 * 2
static constexpr size_t OFF_FEATB = 103367168;            // 3145728 * 2 (bf16 feats)

__device__ __forceinline__ unsigned short f2bf(float f) {
  unsigned u = __float_as_uint(f);
  unsigned r = (u + 0x7FFFu + ((u >> 16) & 1u)) >> 16;   // RNE
  return (unsigned short)r;
}
__device__ __forceinline__ float bf2f(unsigned short h) {
  return __uint_as_float(((unsigned)h) << 16);
}
__device__ __forceinline__ floatx4 mfma_bf16(ushortx8 a, ushortx8 b, floatx4 c) {
  return __builtin_amdgcn_mfma_f32_16x16x32_bf16(
      __builtin_bit_cast(bf16x8, a), __builtin_bit_cast(bf16x8, b), c, 0, 0, 0);
}

// async global->LDS, 16 B per lane. LDS dest = wave-uniform base + lane*16.
__device__ __forceinline__ void gld16(const void* g, void* l) {
  __builtin_amdgcn_global_load_lds(
      (const __attribute__((address_space(1))) unsigned int*)g,
      (__attribute__((address_space(3))) unsigned int*)l, 16, 0, 0);
}

template <int CTRL>
__device__ __forceinline__ float dpp_max(float v) {
  int o = __builtin_amdgcn_update_dpp(0, __float_as_int(v), CTRL, 0xf, 0xf, true);
  return fmaxf(v, __int_as_float(o));
}

// ---------------------------------------------------------------------------
// FPS + PREP merged — r10-MEASURED configuration (214us, VGPR=52): blocks
// 0-7 run the r5-proven 256-thread FPS (4 waves, 8 pts/lane, LDS-staged
// register-resident points — the ONLY shape the allocator keeps in VGPRs;
// 512-thr (r11, VGPR=20) and global-source (r6/r7) variants all fell off the
// residency cliff). Blocks 8+ do the bf16 conversions, hidden under fps.
// Distance math bit-identical to numpy ref; first-index ties exact.
// ---------------------------------------------------------------------------
__global__ __launch_bounds__(256) void fps_prep_kernel(
    const float* __restrict__ points, float* __restrict__ centers,
    const float* __restrict__ W1, const float* __restrict__ Wa,
    const float* __restrict__ Wb, const float* __restrict__ feats,
    unsigned short* __restrict__ W1b, unsigned short* __restrict__ Wab,
    unsigned short* __restrict__ Wbb, unsigned short* __restrict__ featb,
    float* __restrict__ rdenomTab) {
  const int t = threadIdx.x;

  if (blockIdx.x >= 8) {
    // ---- prep path: 1024 elems/block ----
    const int base = (blockIdx.x - 8) * 1024 + t;
#pragma unroll
    for (int j = 0; j < 4; ++j) {
      const int i = base + j * 256;    // < 3440640 by grid construction
      if (i < 147456)        W1b[i] = f2bf(W1[i]);
      else if (i < 221184)   Wab[i - 147456] = f2bf(Wa[i - 147456]);
      else if (i < 294912)   Wbb[i - 221184] = f2bf(Wb[i - 221184]);
      else                   featb[i - 294912] = f2bf(feats[i - 294912]);
    }
    if (blockIdx.x == 8 && t < 64)
      rdenomTab[t] = (float)(1.0 / pow(1000.0, (double)t / 64.0));
    return;
  }

  // ---- fps path (r5 shape, verbatim) ----
  const int b = blockIdx.x;
  const int w = t >> 6, lane = t & 63;
  __shared__ float4 p4[Nn];
  __shared__ unsigned long long wkey[2][4];

  const float* P = points + (size_t)b * Nn * 3;
  for (int n = t; n < Nn; n += 256) {
    float x = P[n * 3], y = P[n * 3 + 1], z = P[n * 3 + 2];
    p4[n] = make_float4(x, y, z, 0.f);
  }
  __syncthreads();

  float rx[8], ry[8], rz[8], dist[8];
#pragma unroll
  for (int k = 0; k < 8; ++k) {
    float4 p = p4[t * 8 + k];       // LDS source -> stays in VGPRs (r5/r9/r10)
    rx[k] = p.x; ry[k] = p.y; rz[k] = p.z;
    dist[k] = INFINITY;
  }

  int cur = 0;
  for (int it = 0; it < Gn; ++it) {
    const float4 c = p4[cur];
    if (t == 0) {
      float* cd = centers + ((size_t)b * Gn + it) * 3;
      cd[0] = c.x; cd[1] = c.y; cd[2] = c.z;
    }
    float bv = -1.0f;
#pragma unroll
    for (int k = 0; k < 8; ++k) {
      float dx = __fsub_rn(rx[k], c.x);
      float dy = __fsub_rn(ry[k], c.y);
      float dz = __fsub_rn(rz[k], c.z);
      float d = __fadd_rn(__fadd_rn(__fmul_rn(dx, dx), __fmul_rn(dy, dy)), __fmul_rn(dz, dz));
      dist[k] = fminf(dist[k], d);
      bv = fmaxf(bv, dist[k]);
    }
    int li = 7;
#pragma unroll
    for (int k = 6; k >= 0; --k) li = (dist[k] == bv) ? k : li;

    float red = bv;
    red = dpp_max<0x111>(red);   // row_shr:1
    red = dpp_max<0x112>(red);   // row_shr:2
    red = dpp_max<0x114>(red);   // row_shr:4
    red = dpp_max<0x118>(red);   // row_shr:8
    red = dpp_max<0x142>(red);   // row_bcast:15
    red = dpp_max<0x143>(red);   // row_bcast:31
    const float M = __int_as_float(__builtin_amdgcn_readlane(__float_as_int(red), 63));

    unsigned long long msk = __ballot(bv == M);
    const int L = __ffsll((long long)msk) - 1;
    const int liL = __builtin_amdgcn_readlane(li, L);
    const int idx = (w * 64 + L) * 8 + liL;

    unsigned long long key =
        ((unsigned long long)__float_as_uint(M) << 32) | (unsigned)(0x7FFFFFFF - idx);
    if (lane == 0) wkey[it & 1][w] = key;
    __syncthreads();
    unsigned long long k0 = wkey[it & 1][0];
    unsigned long long k1 = wkey[it & 1][1];
    unsigned long long k2 = wkey[it & 1][2];
    unsigned long long k3 = wkey[it & 1][3];
    unsigned long long m01 = (k1 > k0) ? k1 : k0;
    unsigned long long m23 = (k3 > k2) ? k3 : k2;
    unsigned long long mm = (m23 > m01) ? m23 : m01;
    cur = 0x7FFFFFFF - (int)(unsigned)mm;
  }
}

// ---------------------------------------------------------------------------
// KNN (wave-per-group, no LDS in hot path) + fused stddev: the last block to
// finish computes 1/(std+eps) (device-scope atomics + fences per G12/G16).
// ---------------------------------------------------------------------------
__global__ __launch_bounds__(256) void knn_kernel(const float* __restrict__ points,
                                                  const float* __restrict__ centers,
                                                  int* __restrict__ knn, int* __restrict__ cidx,
                                                  float* __restrict__ diffb,
                                                  double* __restrict__ sums,
                                                  int* __restrict__ cnt,
                                                  float* __restrict__ stdp) {
  const int t = threadIdx.x;
  const int w = t >> 6, lane = t & 63;
  const int bg = blockIdx.x * 4 + w;
  const int b = bg >> 9;

  const float* P = points + (size_t)b * Nn * 3;
  const float* cc = centers + (size_t)bg * 3;
  const float cx = cc[0], cy = cc[1], cz = cc[2];
  const float aa = __fadd_rn(__fadd_rn(__fmul_rn(cx, cx), __fmul_rn(cy, cy)), __fmul_rn(cz, cz));

  unsigned key[32];
#pragma unroll 8
  for (int s = 0; s < 32; ++s) {
    const int n = s * 64 + lane;
    float X = P[n * 3], Y = P[n * 3 + 1], Z = P[n * 3 + 2];
    float bbv = __fadd_rn(__fadd_rn(__fmul_rn(X, X), __fmul_rn(Y, Y)), __fmul_rn(Z, Z));
    float dot = __fadd_rn(__fadd_rn(__fmul_rn(cx, X), __fmul_rn(cy, Y)), __fmul_rn(cz, Z));
    float d2 = __fsub_rn(__fadd_rn(aa, bbv), __fmul_rn(2.0f, dot));
    unsigned u = __float_as_uint(d2);
    key[s] = u ^ ((unsigned)((int)u >> 31) | 0x80000000u);
  }

  unsigned mk = key[0]; int ms = 0;
#pragma unroll
  for (int s = 1; s < 32; ++s)
    if (key[s] < mk) { mk = key[s]; ms = s; }

  int mysel = 0;
  for (int it = 0; it < Sn; ++it) {
    unsigned long long p = ((unsigned long long)mk << 32) | (unsigned)(ms * 64 + lane);
#pragma unroll
    for (int off = 1; off <= 32; off <<= 1) {
      unsigned long long o = __shfl_xor(p, off, 64);
      p = (o < p) ? o : p;
    }
    const int n_win = (int)(unsigned)p;
    if (lane == it) mysel = n_win;
    if (lane == (n_win & 63)) {
      const int sw = n_win >> 6;
#pragma unroll
      for (int s = 0; s < 32; ++s)
        if (s == sw) key[s] = 0xFFFFFFFFu;
      mk = key[0]; ms = 0;
#pragma unroll
      for (int s = 1; s < 32; ++s)
        if (key[s] < mk) { mk = key[s]; ms = s; }
    }
  }

  double s1 = 0.0, s2 = 0.0;
  if (lane < Sn) {
    knn[(size_t)bg * Sn + lane] = mysel;
    float X = P[mysel * 3], Y = P[mysel * 3 + 1], Z = P[mysel * 3 + 2];
    float dx = __fsub_rn(X, cx), dy = __fsub_rn(Y, cy), dz = __fsub_rn(Z, cz);
    float* db = diffb + (size_t)bg * 96 + lane * 3;
    db[0] = dx; db[1] = dy; db[2] = dz;
    s1 = (double)dx + (double)dy + (double)dz;
    s2 = (double)dx * (double)dx + (double)dy * (double)dy + (double)dz * (double)dz;
  }
#pragma unroll
  for (int off = 1; off <= 32; off <<= 1) {
    s1 += __shfl_xor(s1, off, 64);
    s2 += __shfl_xor(s2, off, 64);
  }
  if (lane == 0) {
    cidx[bg] = __shfl(mysel, 0, 64);
    atomicAdd(sums, s1);
    atomicAdd(sums + 1, s2);
  }
  __threadfence();
  __syncthreads();
  if (t == 0) {
    const int old = atomicAdd(cnt, 1);
    if (old == (Bn * Gn / 4) - 1) {        // last block: compute 1/(std+eps)
      __threadfence();
      const double S1 = atomicAdd(sums, 0.0);
      const double S2 = atomicAdd(sums + 1, 0.0);
      const double n = (double)(Bn * Gn * Sn * 3);
      const double mean = S1 / n;
      const double var = (S2 - S1 * mean) / (n - 1.0);
      const float stdf = (float)sqrt(var) + 1e-5f;
      *stdp = (float)(1.0 / (double)stdf);
    }
  }
}

// ===========================================================================
// GEMM1 (unchanged, r8-r11-proven): gathered [neighbor|center] feats @ W1^T
// + b1, ReLU, fused Fourier pos-embed -> G1 bf16. 128x128 tile, BK=64, gld16.
// ===========================================================================
__global__ __launch_bounds__(256) void gemm1_kernel(
    const unsigned short* __restrict__ featb, const unsigned short* __restrict__ W1b,
    const float* __restrict__ b1, const int* __restrict__ knn,
    const int* __restrict__ cidx, const float* __restrict__ diffb,
    const float* __restrict__ rstd_p, const float* __restrict__ rdenomTab,
    unsigned short* __restrict__ G1) {
  __shared__ unsigned short As[128 * 64];
  __shared__ unsigned short Bs[128 * 64];
  const int t = threadIdx.x;
  const int bm = blockIdx.x, bn = blockIdx.y;
  const int wid = t >> 6, lane = t & 63, quad = lane >> 4, c16 = lane & 15;
  const int wr = wid >> 1, wc = wid & 1;

  int aOffN[4], aOffC[4], bOff[4];
#pragma unroll
  for (int i = 0; i < 4; ++i) {
    const int slot = i * 256 + t;
    const int row = slot >> 3, segV = slot & 7;
    const int seg = segV ^ (row & 7);
    const int grow = bm * 128 + row;
    const int bg = grow >> 5, s = grow & 31, bb_ = bg >> 9;
    const int nidx = knn[(size_t)bg * Sn + s];
    const int ci = cidx[bg];
    aOffN[i] = (bb_ * Nn + nidx) * Dn + seg * 8;
    aOffC[i] = (bb_ * Nn + ci) * Dn + seg * 8;
    bOff[i] = (bn * 128 + row) * 384 + seg * 8;
  }

  floatx4 acc[4][4];
#pragma unroll
  for (int i = 0; i < 4; ++i)
#pragma unroll
    for (int j = 0; j < 4; ++j) acc[i][j] = (floatx4){0.f, 0.f, 0.f, 0.f};

  for (int kt = 0; kt < 6; ++kt) {
    const int kb = kt * 64;
#pragma unroll
    for (int i = 0; i < 4; ++i) {
      const unsigned short* srcA =
          (kt < 3) ? (featb + aOffN[i] + kb) : (featb + aOffC[i] + (kb - 192));
      gld16(srcA, &As[(i * 256 + wid * 64) * 8]);
      gld16(W1b + bOff[i] + kb, &Bs[(i * 256 + wid * 64) * 8]);
    }
    __syncthreads();
#pragma unroll
    for (int ks = 0; ks < 2; ++ks) {
      ushortx8 af[4], bf[4];
#pragma unroll
      for (int mt = 0; mt < 4; ++mt) {
        const int row = wr * 64 + mt * 16 + c16;
        const int seg = (ks * 4 + quad) ^ (row & 7);
        af[mt] = *(const ushortx8*)&As[row * 64 + seg * 8];
      }
#pragma unroll
      for (int nt = 0; nt < 4; ++nt) {
        const int row = wc * 64 + nt * 16 + c16;
        const int seg = (ks * 4 + quad) ^ (row & 7);
        bf[nt] = *(const ushortx8*)&Bs[row * 64 + seg * 8];
      }
#pragma unroll
      for (int mt = 0; mt < 4; ++mt)
#pragma unroll
        for (int nt = 0; nt < 4; ++nt)
          acc[mt][nt] = mfma_bf16(af[mt], bf[nt], acc[mt][nt]);
    }
    __syncthreads();
  }

  const float rstd = *rstd_p;
  float bias[4], rdnm[4];
  bool usin[4];
#pragma unroll
  for (int nt = 0; nt < 4; ++nt) {
    const int col = bn * 128 + wc * 64 + nt * 16 + c16;
    bias[nt] = b1[col];
    const int j = col & 127;
    usin[nt] = (j < 64);
    rdnm[nt] = rdenomTab[j & 63];
  }
#pragma unroll
  for (int mt = 0; mt < 4; ++mt) {
#pragma unroll
    for (int r = 0; r < 4; ++r) {
      const int row = bm * 128 + wr * 64 + mt * 16 + quad * 4 + r;
      const float dv = diffb[(size_t)row * 3 + bn];     // i3 == bn for 128-col blocks
      const float x = __fmul_rn(dv, rstd);
      const float zb = __fmul_rn(100.0f, x);
#pragma unroll
      for (int nt = 0; nt < 4; ++nt) {
        const int col = bn * 128 + wc * 64 + nt * 16 + c16;
        float y = fmaxf(acc[mt][nt][r] + bias[nt], 0.f);
        float z = __fmul_rn(zb, rdnm[nt]);
        float p = usin[nt] ? __sinf(z) : __cosf(z);
        float g = (y + p) * p;
        G1[(size_t)row * 384 + col] = f2bf(g);
      }
    }
  }
}

// ===========================================================================
// GEMM23 (fused residual block) — r9-measured version: 512 threads (8 waves,
// 2x4), 128 rows/block, 100KB LDS. Phase A: Htile[128][192] = relu(G1@Wa^T
// +ba) -> LDS bf16 (stride 200). Phase B: out = relu(Htile@Wb^T+bb+G1) +
// fused max+mean pool -> d_out. (r10's 64-row variant regressed: doubled
// B-matrix re-staging; keep this one.)
// ===========================================================================
__global__ __launch_bounds__(512) void gemm23_kernel(
    const unsigned short* __restrict__ G1, const unsigned short* __restrict__ Wab,
    const float* __restrict__ ba, const unsigned short* __restrict__ Wbb,
    const float* __restrict__ bb, float* __restrict__ outp) {
  __shared__ __align__(16) char smem[100352];
  unsigned short* Htile = (unsigned short*)smem;                  // 128 x 200
  unsigned short* As    = (unsigned short*)(smem + 51200);        // 128 x 64
  unsigned short* BsA   = (unsigned short*)(smem + 51200 + 16384);// 192 x 64
  unsigned short* BsB   = (unsigned short*)(smem + 51200);        // 384 x 64 (aliases As/BsA)

  const int t = threadIdx.x;
  const int bm = blockIdx.x;
  const int lane = t & 63, quad = lane >> 4, c16 = lane & 15;
  const int wid = t >> 6;
  const int wr = wid >> 2, wc = wid & 3;    // 2 x 4 wave grid

  // ---------------- Phase A: Htile = relu(G1 @ Wa^T + ba), K=384 ----------
  int aOff[2], bOffA[3];
#pragma unroll
  for (int i = 0; i < 2; ++i) {
    const int slot = i * 512 + t;
    const int row = slot >> 3, segV = slot & 7;
    aOff[i] = (bm * 128 + row) * 384 + (segV ^ (row & 7)) * 8;
  }
#pragma unroll
  for (int i = 0; i < 3; ++i) {
    const int slot = i * 512 + t;
    const int row = slot >> 3, segV = slot & 7;
    bOffA[i] = row * 384 + (segV ^ (row & 7)) * 8;
  }

  floatx4 accA[4][3];
#pragma unroll
  for (int i = 0; i < 4; ++i)
#pragma unroll
    for (int j = 0; j < 3; ++j) accA[i][j] = (floatx4){0.f, 0.f, 0.f, 0.f};

  for (int kt = 0; kt < 6; ++kt) {
    const int kb = kt * 64;
#pragma unroll
    for (int i = 0; i < 2; ++i) gld16(G1 + aOff[i] + kb, As + ((size_t)(i * 512 + t)) * 8);
#pragma unroll
    for (int i = 0; i < 3; ++i) gld16(Wab + bOffA[i] + kb, BsA + ((size_t)(i * 512 + t)) * 8);
    __syncthreads();
#pragma unroll
    for (int ks = 0; ks < 2; ++ks) {
      ushortx8 af[4], bf[3];
#pragma unroll
      for (int mt = 0; mt < 4; ++mt) {
        const int row = wr * 64 + mt * 16 + c16;
        const int seg = (ks * 4 + quad) ^ (row & 7);
        af[mt] = *(const ushortx8*)&As[row * 64 + seg * 8];
      }
#pragma unroll
      for (int nt = 0; nt < 3; ++nt) {
        const int row = wc * 48 + nt * 16 + c16;       // < 192
        const int seg = (ks * 4 + quad) ^ (row & 7);
        bf[nt] = *(const ushortx8*)&BsA[row * 64 + seg * 8];
      }
#pragma unroll
      for (int mt = 0; mt < 4; ++mt)
#pragma unroll
        for (int nt = 0; nt < 3; ++nt)
          accA[mt][nt] = mfma_bf16(af[mt], bf[nt], accA[mt][nt]);
    }
    __syncthreads();
  }

  // write H tile to LDS (bf16 — same rounding as a global round-trip)
#pragma unroll
  for (int nt = 0; nt < 3; ++nt) {
    const int col = wc * 48 + nt * 16 + c16;
    const float bias = ba[col];
#pragma unroll
    for (int mt = 0; mt < 4; ++mt)
#pragma unroll
      for (int r = 0; r < 4; ++r) {
        const int row = wr * 64 + mt * 16 + quad * 4 + r;
        Htile[row * 200 + col] = f2bf(fmaxf(accA[mt][nt][r] + bias, 0.f));
      }
  }
  __syncthreads();

  // ---------------- Phase B: out = relu(Htile @ Wb^T + bb + G1) + pool ----
  int bOffB[6];
#pragma unroll
  for (int i = 0; i < 6; ++i) {
    const int slot = i * 512 + t;
    const int row = slot >> 3, segV = slot & 7;
    bOffB[i] = row * 192 + (segV ^ (row & 7)) * 8;
  }

  floatx4 acc[4][6];
#pragma unroll
  for (int i = 0; i < 4; ++i)
#pragma unroll
    for (int j = 0; j < 6; ++j) acc[i][j] = (floatx4){0.f, 0.f, 0.f, 0.f};

  for (int kt = 0; kt < 3; ++kt) {
    const int kb = kt * 64;
#pragma unroll
    for (int i = 0; i < 6; ++i) gld16(Wbb + bOffB[i] + kb, BsB + ((size_t)(i * 512 + t)) * 8);
    __syncthreads();
#pragma unroll
    for (int ks = 0; ks < 2; ++ks) {
      ushortx8 af[4], bf[6];
#pragma unroll
      for (int mt = 0; mt < 4; ++mt) {
        const int row = wr * 64 + mt * 16 + c16;
        af[mt] = *(const ushortx8*)&Htile[row * 200 + kb + ks * 32 + quad * 8];
      }
#pragma unroll
      for (int nt = 0; nt < 6; ++nt) {
        const int row = wc * 96 + nt * 16 + c16;       // < 384
        const int seg = (ks * 4 + quad) ^ (row & 7);
        bf[nt] = *(const ushortx8*)&BsB[row * 64 + seg * 8];
      }
#pragma unroll
      for (int mt = 0; mt < 4; ++mt)
#pragma unroll
        for (int nt = 0; nt < 6; ++nt)
          acc[mt][nt] = mfma_bf16(af[mt], bf[nt], acc[mt][nt]);
    }
    __syncthreads();
  }

#pragma unroll
  for (int nt = 0; nt < 6; ++nt) {
    const int col = wc * 96 + nt * 16 + c16;
    const float bias = bb[col];
    float gmax[2] = {-INFINITY, -INFINITY};
    float gsum[2] = {0.f, 0.f};
#pragma unroll
    for (int mt = 0; mt < 4; ++mt) {
      const int grp = mt >> 1;
#pragma unroll
      for (int r = 0; r < 4; ++r) {
        const int row = bm * 128 + wr * 64 + mt * 16 + quad * 4 + r;
        float v = acc[mt][nt][r] + bias + bf2f(G1[(size_t)row * 384 + col]);
        v = fmaxf(v, 0.f);
        gmax[grp] = fmaxf(gmax[grp], v);
        gsum[grp] += v;
      }
    }
#pragma unroll
    for (int grp = 0; grp < 2; ++grp) {
      float m = gmax[grp], su = gsum[grp];
#pragma unroll
      for (int off = 16; off <= 32; off <<= 1) {
        m = fmaxf(m, __shfl_xor(m, off, 64));
        su += __shfl_xor(su, off, 64);
      }
      if (quad == 0) {
        const int bg = bm * 4 + wr * 2 + grp;
        outp[(size_t)bg * 384 + col] = m + su / 32.0f;
      }
    }
  }
}

// ---------------------------------------------------------------------------
extern "C" void kernel_launch(void* const* d_in, const int* in_sizes, int n_in,
                              void* d_out, int out_size, void* d_ws, size_t ws_size,
                              hipStream_t stream) {
  const float* points = (const float*)d_in[0];
  const float* feats  = (const float*)d_in[1];
  const float* W1 = (const float*)d_in[2];
  const float* b1 = (const float*)d_in[3];
  const float* Wa = (const float*)d_in[4];
  const float* ba = (const float*)d_in[5];
  const float* Wb = (const float*)d_in[6];
  const float* bb = (const float*)d_in[7];
  float* outF = (float*)d_out;

  char* ws = (char*)d_ws;
  int*            knn      = (int*)(ws + OFF_KNN);
  int*            cidx     = (int*)(ws + OFF_CIDX);
  float*          diffb    = (float*)(ws + OFF_DIFF);
  double*         sums     = (double*)(ws + OFF_SUMS);
  float*          stdp     = (float*)(ws + OFF_STD);
  int*            cnt      = (int*)(ws + OFF_CNT);
  float*          rdenomTab= (float*)(ws + OFF_DENOM);
  unsigned short* W1b      = (unsigned short*)(ws + OFF_W1B);
  unsigned short* Wab      = (unsigned short*)(ws + OFF_WAB);
  unsigned short* Wbb      = (unsigned short*)(ws + OFF_WBB);
  unsigned short* G1       = (unsigned short*)(ws + OFF_G1);
  unsigned short* featb    = (unsigned short*)(ws + OFF_FEATB);

  // zero sums(16B) + stdp(4B, rewritten by knn) + cnt(4B) in one memset
  hipMemsetAsync(ws + OFF_SUMS, 0, 40, stream);
  fps_prep_kernel<<<8 + 3360, 256, 0, stream>>>(points, outF, W1, Wa, Wb, feats,
                                                W1b, Wab, Wbb, featb, rdenomTab);
  knn_kernel<<<Bn * Gn / 4, 256, 0, stream>>>(points, outF, knn, cidx, diffb,
                                              sums, cnt, stdp);
  gemm1_kernel<<<dim3(Mrows / 128, 3), 256, 0, stream>>>(featb, W1b, b1, knn, cidx,
                                                         diffb, stdp, rdenomTab, G1);
  gemm23_kernel<<<Mrows / 128, 512, 0, stream>>>(G1, Wab, ba, Wbb, bb, outF + Bn * Gn * 3);
}

// Round 13
// 459.765 us; speedup vs baseline: 1.4691x; 1.2580x over previous
//
#include <hip/hip_runtime.h>
#include <math.h>

// Problem constants
#define Bn   8
#define Nn   2048
#define Dn   192
#define Gn   512
#define Sn   32
#define OUTn 384
#define Mrows (Bn * Gn * Sn)   // 131072 rows through the MLP

typedef __attribute__((ext_vector_type(8))) unsigned short ushortx8;
typedef __attribute__((ext_vector_type(8))) __bf16 bf16x8;
typedef __attribute__((ext_vector_type(4))) float floatx4;

// ---------- ws layout (bytes) ----------
static constexpr size_t OFF_KNN    = 0;                    // 131072 * 4
static constexpr size_t OFF_CIDX   = 524288;               // 4096 * 4
static constexpr size_t OFF_DIFF   = 540672;               // 393216 * 4
static constexpr size_t OFF_SUMS   = 2113536;              // 2 doubles
static constexpr size_t OFF_STD    = 2113552;              // 1 float (stores 1/std)
static constexpr size_t OFF_CNT    = 2113568;              // 1 int (knn done counter)
static constexpr size_t OFF_DENOM  = 2113792;              // 64 floats (stores 1/denom)
static constexpr size_t OFF_W1B    = 2114048;              // 147456 * 2
static constexpr size_t OFF_WAB    = 2408960;              // 73728 * 2
static constexpr size_t OFF_WBB    = 2556416;               // 73728 * 2
static constexpr size_t OFF_G1     = 2703872;              // 50331648 * 2
static constexpr size_t OFF_FEATB  = 103367168;            // 3145728 * 2 (bf16 feats)
static constexpr size_t OFF_CSTAGE = 109658624;            // 12288 * 4 (staged centers, 0xFF sentinel)

__device__ __forceinline__ unsigned short f2bf(float f) {
  unsigned u = __float_as_uint(f);
  unsigned r = (u + 0x7FFFu + ((u >> 16) & 1u)) >> 16;   // RNE
  return (unsigned short)r;
}
__device__ __forceinline__ float bf2f(unsigned short h) {
  return __uint_as_float(((unsigned)h) << 16);
}
__device__ __forceinline__ floatx4 mfma_bf16(ushortx8 a, ushortx8 b, floatx4 c) {
  return __builtin_amdgcn_mfma_f32_16x16x32_bf16(
      __builtin_bit_cast(bf16x8, a), __builtin_bit_cast(bf16x8, b), c, 0, 0, 0);
}

// async global->LDS, 16 B per lane. LDS dest = wave-uniform base + lane*16.
__device__ __forceinline__ void gld16(const void* g, void* l) {
  __builtin_amdgcn_global_load_lds(
      (const __attribute__((address_space(1))) unsigned int*)g,
      (__attribute__((address_space(3))) unsigned int*)l, 16, 0, 0);
}

template <int CTRL>
__device__ __forceinline__ float dpp_max(float v) {
  int o = __builtin_amdgcn_update_dpp(0, __float_as_int(v), CTRL, 0xf, 0xf, true);
  return fmaxf(v, __int_as_float(o));
}

// ---------------------------------------------------------------------------
// FUSED FRONT: fps (blocks 0-7) + prep (8..3367) + knn (3368..4391) in ONE
// launch so knn overlaps fps. knn group g needs only ITS center, which fps
// finalizes at iteration g: fps publishes each center to a sentinel-inited
// staging buffer with relaxed AGENT-scope stores (cross-XCD visible, G16);
// knn waves spin on the value (s_sleep-throttled agent loads). Deadlock-free:
// the only dependency edge is knn->fps, fps waits on nobody, and its 8
// blocks are first in the grid. fps path itself is the r5/r10-proven shape
// (256 thr, 8 pts/lane, LDS-staged register-resident points, VGPR=52,
// 214-218us measured). Distance math bit-identical to numpy ref everywhere;
// first-index ties exact.
// ---------------------------------------------------------------------------
__global__ __launch_bounds__(256) void fused_front_kernel(
    const float* __restrict__ points, float* __restrict__ centers,
    const float* __restrict__ W1, const float* __restrict__ Wa,
    const float* __restrict__ Wb, const float* __restrict__ feats,
    unsigned short* __restrict__ W1b, unsigned short* __restrict__ Wab,
    unsigned short* __restrict__ Wbb, unsigned short* __restrict__ featb,
    float* __restrict__ rdenomTab, float* __restrict__ cstage,
    int* __restrict__ knn, int* __restrict__ cidx, float* __restrict__ diffb,
    double* __restrict__ sums, int* __restrict__ cnt, float* __restrict__ stdp) {
  const int t = threadIdx.x;
  const int w = t >> 6, lane = t & 63;

  if (blockIdx.x >= 8 && blockIdx.x < 8 + 3360) {
    // ---- prep path: 1024 elems/block ----
    const int base = (blockIdx.x - 8) * 1024 + t;
#pragma unroll
    for (int j = 0; j < 4; ++j) {
      const int i = base + j * 256;    // < 3440640 by grid construction
      if (i < 147456)        W1b[i] = f2bf(W1[i]);
      else if (i < 221184)   Wab[i - 147456] = f2bf(Wa[i - 147456]);
      else if (i < 294912)   Wbb[i - 221184] = f2bf(Wb[i - 221184]);
      else                   featb[i - 294912] = f2bf(feats[i - 294912]);
    }
    if (blockIdx.x == 8 && t < 64)
      rdenomTab[t] = (float)(1.0 / pow(1000.0, (double)t / 64.0));
    return;
  }

  if (blockIdx.x >= 8 + 3360) {
    // ---- knn path (wave-per-group): spin for this group's center ----
    const int bg = (blockIdx.x - 3368) * 4 + w;
    const int b = bg >> 9;
    const float* P = points + (size_t)b * Nn * 3;
    const unsigned* cs = (const unsigned*)(cstage + (size_t)bg * 3);

    unsigned ux, uy, uz;
    for (;;) {
      ux = __hip_atomic_load(cs + 0, __ATOMIC_RELAXED, __HIP_MEMORY_SCOPE_AGENT);
      uy = __hip_atomic_load(cs + 1, __ATOMIC_RELAXED, __HIP_MEMORY_SCOPE_AGENT);
      uz = __hip_atomic_load(cs + 2, __ATOMIC_RELAXED, __HIP_MEMORY_SCOPE_AGENT);
      if (ux != 0xFFFFFFFFu && uy != 0xFFFFFFFFu && uz != 0xFFFFFFFFu) break;
      __builtin_amdgcn_s_sleep(16);
    }
    const float cx = __uint_as_float(ux);
    const float cy = __uint_as_float(uy);
    const float cz = __uint_as_float(uz);
    const float aa = __fadd_rn(__fadd_rn(__fmul_rn(cx, cx), __fmul_rn(cy, cy)), __fmul_rn(cz, cz));

    unsigned key[32];
#pragma unroll 8
    for (int s = 0; s < 32; ++s) {
      const int n = s * 64 + lane;
      float X = P[n * 3], Y = P[n * 3 + 1], Z = P[n * 3 + 2];
      float bbv = __fadd_rn(__fadd_rn(__fmul_rn(X, X), __fmul_rn(Y, Y)), __fmul_rn(Z, Z));
      float dot = __fadd_rn(__fadd_rn(__fmul_rn(cx, X), __fmul_rn(cy, Y)), __fmul_rn(cz, Z));
      float d2 = __fsub_rn(__fadd_rn(aa, bbv), __fmul_rn(2.0f, dot));
      unsigned u = __float_as_uint(d2);
      key[s] = u ^ ((unsigned)((int)u >> 31) | 0x80000000u);
    }

    unsigned mk = key[0]; int ms = 0;
#pragma unroll
    for (int s = 1; s < 32; ++s)
      if (key[s] < mk) { mk = key[s]; ms = s; }

    int mysel = 0;
    for (int it = 0; it < Sn; ++it) {
      unsigned long long p = ((unsigned long long)mk << 32) | (unsigned)(ms * 64 + lane);
#pragma unroll
      for (int off = 1; off <= 32; off <<= 1) {
        unsigned long long o = __shfl_xor(p, off, 64);
        p = (o < p) ? o : p;
      }
      const int n_win = (int)(unsigned)p;
      if (lane == it) mysel = n_win;
      if (lane == (n_win & 63)) {
        const int sw = n_win >> 6;
#pragma unroll
        for (int s = 0; s < 32; ++s)
          if (s == sw) key[s] = 0xFFFFFFFFu;
        mk = key[0]; ms = 0;
#pragma unroll
        for (int s = 1; s < 32; ++s)
          if (key[s] < mk) { mk = key[s]; ms = s; }
      }
    }

    double s1 = 0.0, s2 = 0.0;
    if (lane < Sn) {
      knn[(size_t)bg * Sn + lane] = mysel;
      float X = P[mysel * 3], Y = P[mysel * 3 + 1], Z = P[mysel * 3 + 2];
      float dx = __fsub_rn(X, cx), dy = __fsub_rn(Y, cy), dz = __fsub_rn(Z, cz);
      float* db = diffb + (size_t)bg * 96 + lane * 3;
      db[0] = dx; db[1] = dy; db[2] = dz;
      s1 = (double)dx + (double)dy + (double)dz;
      s2 = (double)dx * (double)dx + (double)dy * (double)dy + (double)dz * (double)dz;
    }
#pragma unroll
    for (int off = 1; off <= 32; off <<= 1) {
      s1 += __shfl_xor(s1, off, 64);
      s2 += __shfl_xor(s2, off, 64);
    }
    if (lane == 0) {
      cidx[bg] = __shfl(mysel, 0, 64);
      atomicAdd(sums, s1);
      atomicAdd(sums + 1, s2);
    }
    __threadfence();
    __syncthreads();
    if (t == 0) {
      const int old = atomicAdd(cnt, 1);
      if (old == (Bn * Gn / 4) - 1) {      // last knn block: 1/(std+eps)
        __threadfence();
        const double S1 = atomicAdd(sums, 0.0);
        const double S2 = atomicAdd(sums + 1, 0.0);
        const double n = (double)(Bn * Gn * Sn * 3);
        const double mean = S1 / n;
        const double var = (S2 - S1 * mean) / (n - 1.0);
        const float stdf = (float)sqrt(var) + 1e-5f;
        *stdp = (float)(1.0 / (double)stdf);
      }
    }
    return;
  }

  // ---- fps path (r5 shape, verbatim + agent-scope center publication) ----
  const int b = blockIdx.x;
  __shared__ float4 p4[Nn];
  __shared__ unsigned long long wkey[2][4];

  const float* P = points + (size_t)b * Nn * 3;
  for (int n = t; n < Nn; n += 256) {
    float x = P[n * 3], y = P[n * 3 + 1], z = P[n * 3 + 2];
    p4[n] = make_float4(x, y, z, 0.f);
  }
  __syncthreads();

  float rx[8], ry[8], rz[8], dist[8];
#pragma unroll
  for (int k = 0; k < 8; ++k) {
    float4 p = p4[t * 8 + k];       // LDS source -> stays in VGPRs (r5/r9/r10)
    rx[k] = p.x; ry[k] = p.y; rz[k] = p.z;
    dist[k] = INFINITY;
  }

  int cur = 0;
  for (int it = 0; it < Gn; ++it) {
    const float4 c = p4[cur];
    if (t == 0) {
      float* cd = centers + ((size_t)b * Gn + it) * 3;
      cd[0] = c.x; cd[1] = c.y; cd[2] = c.z;
      unsigned* cs = (unsigned*)(cstage + ((size_t)b * Gn + it) * 3);
      __hip_atomic_store(cs + 0, __float_as_uint(c.x), __ATOMIC_RELAXED, __HIP_MEMORY_SCOPE_AGENT);
      __hip_atomic_store(cs + 1, __float_as_uint(c.y), __ATOMIC_RELAXED, __HIP_MEMORY_SCOPE_AGENT);
      __hip_atomic_store(cs + 2, __float_as_uint(c.z), __ATOMIC_RELAXED, __HIP_MEMORY_SCOPE_AGENT);
    }
    float bv = -1.0f;
#pragma unroll
    for (int k = 0; k < 8; ++k) {
      float dx = __fsub_rn(rx[k], c.x);
      float dy = __fsub_rn(ry[k], c.y);
      float dz = __fsub_rn(rz[k], c.z);
      float d = __fadd_rn(__fadd_rn(__fmul_rn(dx, dx), __fmul_rn(dy, dy)), __fmul_rn(dz, dz));
      dist[k] = fminf(dist[k], d);
      bv = fmaxf(bv, dist[k]);
    }
    int li = 7;
#pragma unroll
    for (int k = 6; k >= 0; --k) li = (dist[k] == bv) ? k : li;

    float red = bv;
    red = dpp_max<0x111>(red);   // row_shr:1
    red = dpp_max<0x112>(red);   // row_shr:2
    red = dpp_max<0x114>(red);   // row_shr:4
    red = dpp_max<0x118>(red);   // row_shr:8
    red = dpp_max<0x142>(red);   // row_bcast:15
    red = dpp_max<0x143>(red);   // row_bcast:31
    const float M = __int_as_float(__builtin_amdgcn_readlane(__float_as_int(red), 63));

    unsigned long long msk = __ballot(bv == M);
    const int L = __ffsll((long long)msk) - 1;
    const int liL = __builtin_amdgcn_readlane(li, L);
    const int idx = (w * 64 + L) * 8 + liL;

    unsigned long long key =
        ((unsigned long long)__float_as_uint(M) << 32) | (unsigned)(0x7FFFFFFF - idx);
    if (lane == 0) wkey[it & 1][w] = key;
    __syncthreads();
    unsigned long long k0 = wkey[it & 1][0];
    unsigned long long k1 = wkey[it & 1][1];
    unsigned long long k2 = wkey[it & 1][2];
    unsigned long long k3 = wkey[it & 1][3];
    unsigned long long m01 = (k1 > k0) ? k1 : k0;
    unsigned long long m23 = (k3 > k2) ? k3 : k2;
    unsigned long long mm = (m23 > m01) ? m23 : m01;
    cur = 0x7FFFFFFF - (int)(unsigned)mm;
  }
}

// ===========================================================================
// GEMM1 (unchanged, r8-r12-proven): gathered [neighbor|center] feats @ W1^T
// + b1, ReLU, fused Fourier pos-embed -> G1 bf16. 128x128 tile, BK=64, gld16.
// ===========================================================================
__global__ __launch_bounds__(256) void gemm1_kernel(
    const unsigned short* __restrict__ featb, const unsigned short* __restrict__ W1b,
    const float* __restrict__ b1, const int* __restrict__ knn,
    const int* __restrict__ cidx, const float* __restrict__ diffb,
    const float* __restrict__ rstd_p, const float* __restrict__ rdenomTab,
    unsigned short* __restrict__ G1) {
  __shared__ unsigned short As[128 * 64];
  __shared__ unsigned short Bs[128 * 64];
  const int t = threadIdx.x;
  const int bm = blockIdx.x, bn = blockIdx.y;
  const int wid = t >> 6, lane = t & 63, quad = lane >> 4, c16 = lane & 15;
  const int wr = wid >> 1, wc = wid & 1;

  int aOffN[4], aOffC[4], bOff[4];
#pragma unroll
  for (int i = 0; i < 4; ++i) {
    const int slot = i * 256 + t;
    const int row = slot >> 3, segV = slot & 7;
    const int seg = segV ^ (row & 7);
    const int grow = bm * 128 + row;
    const int bg = grow >> 5, s = grow & 31, bb_ = bg >> 9;
    const int nidx = knn[(size_t)bg * Sn + s];
    const int ci = cidx[bg];
    aOffN[i] = (bb_ * Nn + nidx) * Dn + seg * 8;
    aOffC[i] = (bb_ * Nn + ci) * Dn + seg * 8;
    bOff[i] = (bn * 128 + row) * 384 + seg * 8;
  }

  floatx4 acc[4][4];
#pragma unroll
  for (int i = 0; i < 4; ++i)
#pragma unroll
    for (int j = 0; j < 4; ++j) acc[i][j] = (floatx4){0.f, 0.f, 0.f, 0.f};

  for (int kt = 0; kt < 6; ++kt) {
    const int kb = kt * 64;
#pragma unroll
    for (int i = 0; i < 4; ++i) {
      const unsigned short* srcA =
          (kt < 3) ? (featb + aOffN[i] + kb) : (featb + aOffC[i] + (kb - 192));
      gld16(srcA, &As[(i * 256 + wid * 64) * 8]);
      gld16(W1b + bOff[i] + kb, &Bs[(i * 256 + wid * 64) * 8]);
    }
    __syncthreads();
#pragma unroll
    for (int ks = 0; ks < 2; ++ks) {
      ushortx8 af[4], bf[4];
#pragma unroll
      for (int mt = 0; mt < 4; ++mt) {
        const int row = wr * 64 + mt * 16 + c16;
        const int seg = (ks * 4 + quad) ^ (row & 7);
        af[mt] = *(const ushortx8*)&As[row * 64 + seg * 8];
      }
#pragma unroll
      for (int nt = 0; nt < 4; ++nt) {
        const int row = wc * 64 + nt * 16 + c16;
        const int seg = (ks * 4 + quad) ^ (row & 7);
        bf[nt] = *(const ushortx8*)&Bs[row * 64 + seg * 8];
      }
#pragma unroll
      for (int mt = 0; mt < 4; ++mt)
#pragma unroll
        for (int nt = 0; nt < 4; ++nt)
          acc[mt][nt] = mfma_bf16(af[mt], bf[nt], acc[mt][nt]);
    }
    __syncthreads();
  }

  const float rstd = *rstd_p;
  float bias[4], rdnm[4];
  bool usin[4];
#pragma unroll
  for (int nt = 0; nt < 4; ++nt) {
    const int col = bn * 128 + wc * 64 + nt * 16 + c16;
    bias[nt] = b1[col];
    const int j = col & 127;
    usin[nt] = (j < 64);
    rdnm[nt] = rdenomTab[j & 63];
  }
#pragma unroll
  for (int mt = 0; mt < 4; ++mt) {
#pragma unroll
    for (int r = 0; r < 4; ++r) {
      const int row = bm * 128 + wr * 64 + mt * 16 + quad * 4 + r;
      const float dv = diffb[(size_t)row * 3 + bn];     // i3 == bn for 128-col blocks
      const float x = __fmul_rn(dv, rstd);
      const float zb = __fmul_rn(100.0f, x);
#pragma unroll
      for (int nt = 0; nt < 4; ++nt) {
        const int col = bn * 128 + wc * 64 + nt * 16 + c16;
        float y = fmaxf(acc[mt][nt][r] + bias[nt], 0.f);
        float z = __fmul_rn(zb, rdnm[nt]);
        float p = usin[nt] ? __sinf(z) : __cosf(z);
        float g = (y + p) * p;
        G1[(size_t)row * 384 + col] = f2bf(g);
      }
    }
  }
}

// ===========================================================================
// GEMM23 (fused residual block) — r9-measured version: 512 threads (8 waves,
// 2x4), 128 rows/block, 100KB LDS. Phase A: Htile[128][192] = relu(G1@Wa^T
// +ba) -> LDS bf16 (stride 200). Phase B: out = relu(Htile@Wb^T+bb+G1) +
// fused max+mean pool -> d_out.
// ===========================================================================
__global__ __launch_bounds__(512) void gemm23_kernel(
    const unsigned short* __restrict__ G1, const unsigned short* __restrict__ Wab,
    const float* __restrict__ ba, const unsigned short* __restrict__ Wbb,
    const float* __restrict__ bb, float* __restrict__ outp) {
  __shared__ __align__(16) char smem[100352];
  unsigned short* Htile = (unsigned short*)smem;                  // 128 x 200
  unsigned short* As    = (unsigned short*)(smem + 51200);        // 128 x 64
  unsigned short* BsA   = (unsigned short*)(smem + 51200 + 16384);// 192 x 64
  unsigned short* BsB   = (unsigned short*)(smem + 51200);        // 384 x 64 (aliases As/BsA)

  const int t = threadIdx.x;
  const int bm = blockIdx.x;
  const int lane = t & 63, quad = lane >> 4, c16 = lane & 15;
  const int wid = t >> 6;
  const int wr = wid >> 2, wc = wid & 3;    // 2 x 4 wave grid

  // ---------------- Phase A: Htile = relu(G1 @ Wa^T + ba), K=384 ----------
  int aOff[2], bOffA[3];
#pragma unroll
  for (int i = 0; i < 2; ++i) {
    const int slot = i * 512 + t;
    const int row = slot >> 3, segV = slot & 7;
    aOff[i] = (bm * 128 + row) * 384 + (segV ^ (row & 7)) * 8;
  }
#pragma unroll
  for (int i = 0; i < 3; ++i) {
    const int slot = i * 512 + t;
    const int row = slot >> 3, segV = slot & 7;
    bOffA[i] = row * 384 + (segV ^ (row & 7)) * 8;
  }

  floatx4 accA[4][3];
#pragma unroll
  for (int i = 0; i < 4; ++i)
#pragma unroll
    for (int j = 0; j < 3; ++j) accA[i][j] = (floatx4){0.f, 0.f, 0.f, 0.f};

  for (int kt = 0; kt < 6; ++kt) {
    const int kb = kt * 64;
#pragma unroll
    for (int i = 0; i < 2; ++i) gld16(G1 + aOff[i] + kb, As + ((size_t)(i * 512 + t)) * 8);
#pragma unroll
    for (int i = 0; i < 3; ++i) gld16(Wab + bOffA[i] + kb, BsA + ((size_t)(i * 512 + t)) * 8);
    __syncthreads();
#pragma unroll
    for (int ks = 0; ks < 2; ++ks) {
      ushortx8 af[4], bf[3];
#pragma unroll
      for (int mt = 0; mt < 4; ++mt) {
        const int row = wr * 64 + mt * 16 + c16;
        const int seg = (ks * 4 + quad) ^ (row & 7);
        af[mt] = *(const ushortx8*)&As[row * 64 + seg * 8];
      }
#pragma unroll
      for (int nt = 0; nt < 3; ++nt) {
        const int row = wc * 48 + nt * 16 + c16;       // < 192
        const int seg = (ks * 4 + quad) ^ (row & 7);
        bf[nt] = *(const ushortx8*)&BsA[row * 64 + seg * 8];
      }
#pragma unroll
      for (int mt = 0; mt < 4; ++mt)
#pragma unroll
        for (int nt = 0; nt < 3; ++nt)
          accA[mt][nt] = mfma_bf16(af[mt], bf[nt], accA[mt][nt]);
    }
    __syncthreads();
  }

  // write H tile to LDS (bf16 — same rounding as a global round-trip)
#pragma unroll
  for (int nt = 0; nt < 3; ++nt) {
    const int col = wc * 48 + nt * 16 + c16;
    const float bias = ba[col];
#pragma unroll
    for (int mt = 0; mt < 4; ++mt)
#pragma unroll
      for (int r = 0; r < 4; ++r) {
        const int row = wr * 64 + mt * 16 + quad * 4 + r;
        Htile[row * 200 + col] = f2bf(fmaxf(accA[mt][nt][r] + bias, 0.f));
      }
  }
  __syncthreads();

  // ---------------- Phase B: out = relu(Htile @ Wb^T + bb + G1) + pool ----
  int bOffB[6];
#pragma unroll
  for (int i = 0; i < 6; ++i) {
    const int slot = i * 512 + t;
    const int row = slot >> 3, segV = slot & 7;
    bOffB[i] = row * 192 + (segV ^ (row & 7)) * 8;
  }

  floatx4 acc[4][6];
#pragma unroll
  for (int i = 0; i < 4; ++i)
#pragma unroll
    for (int j = 0; j < 6; ++j) acc[i][j] = (floatx4){0.f, 0.f, 0.f, 0.f};

  for (int kt = 0; kt < 3; ++kt) {
    const int kb = kt * 64;
#pragma unroll
    for (int i = 0; i < 6; ++i) gld16(Wbb + bOffB[i] + kb, BsB + ((size_t)(i * 512 + t)) * 8);
    __syncthreads();
#pragma unroll
    for (int ks = 0; ks < 2; ++ks) {
      ushortx8 af[4], bf[6];
#pragma unroll
      for (int mt = 0; mt < 4; ++mt) {
        const int row = wr * 64 + mt * 16 + c16;
        af[mt] = *(const ushortx8*)&Htile[row * 200 + kb + ks * 32 + quad * 8];
      }
#pragma unroll
      for (int nt = 0; nt < 6; ++nt) {
        const int row = wc * 96 + nt * 16 + c16;       // < 384
        const int seg = (ks * 4 + quad) ^ (row & 7);
        bf[nt] = *(const ushortx8*)&BsB[row * 64 + seg * 8];
      }
#pragma unroll
      for (int mt = 0; mt < 4; ++mt)
#pragma unroll
        for (int nt = 0; nt < 6; ++nt)
          acc[mt][nt] = mfma_bf16(af[mt], bf[nt], acc[mt][nt]);
    }
    __syncthreads();
  }

#pragma unroll
  for (int nt = 0; nt < 6; ++nt) {
    const int col = wc * 96 + nt * 16 + c16;
    const float bias = bb[col];
    float gmax[2] = {-INFINITY, -INFINITY};
    float gsum[2] = {0.f, 0.f};
#pragma unroll
    for (int mt = 0; mt < 4; ++mt) {
      const int grp = mt >> 1;
#pragma unroll
      for (int r = 0; r < 4; ++r) {
        const int row = bm * 128 + wr * 64 + mt * 16 + quad * 4 + r;
        float v = acc[mt][nt][r] + bias + bf2f(G1[(size_t)row * 384 + col]);
        v = fmaxf(v, 0.f);
        gmax[grp] = fmaxf(gmax[grp], v);
        gsum[grp] += v;
      }
    }
#pragma unroll
    for (int grp = 0; grp < 2; ++grp) {
      float m = gmax[grp], su = gsum[grp];
#pragma unroll
      for (int off = 16; off <= 32; off <<= 1) {
        m = fmaxf(m, __shfl_xor(m, off, 64));
        su += __shfl_xor(su, off, 64);
      }
      if (quad == 0) {
        const int bg = bm * 4 + wr * 2 + grp;
        outp[(size_t)bg * 384 + col] = m + su / 32.0f;
      }
    }
  }
}

// ---------------------------------------------------------------------------
extern "C" void kernel_launch(void* const* d_in, const int* in_sizes, int n_in,
                              void* d_out, int out_size, void* d_ws, size_t ws_size,
                              hipStream_t stream) {
  const float* points = (const float*)d_in[0];
  const float* feats  = (const float*)d_in[1];
  const float* W1 = (const float*)d_in[2];
  const float* b1 = (const float*)d_in[3];
  const float* Wa = (const float*)d_in[4];
  const float* ba = (const float*)d_in[5];
  const float* Wb = (const float*)d_in[6];
  const float* bb = (const float*)d_in[7];
  float* outF = (float*)d_out;

  char* ws = (char*)d_ws;
  int*            knn      = (int*)(ws + OFF_KNN);
  int*            cidx     = (int*)(ws + OFF_CIDX);
  float*          diffb    = (float*)(ws + OFF_DIFF);
  double*         sums     = (double*)(ws + OFF_SUMS);
  float*          stdp     = (float*)(ws + OFF_STD);
  int*            cnt      = (int*)(ws + OFF_CNT);
  float*          rdenomTab= (float*)(ws + OFF_DENOM);
  unsigned short* W1b      = (unsigned short*)(ws + OFF_W1B);
  unsigned short* Wab      = (unsigned short*)(ws + OFF_WAB);
  unsigned short* Wbb      = (unsigned short*)(ws + OFF_WBB);
  unsigned short* G1       = (unsigned short*)(ws + OFF_G1);
  unsigned short* featb    = (unsigned short*)(ws + OFF_FEATB);
  float*          cstage   = (float*)(ws + OFF_CSTAGE);

  // zero sums(16B) + stdp + cnt; sentinel-init staged centers (0xFF = NaN)
  hipMemsetAsync(ws + OFF_SUMS, 0, 40, stream);
  hipMemsetAsync(ws + OFF_CSTAGE, 0xFF, (size_t)Bn * Gn * 3 * 4, stream);
  fused_front_kernel<<<8 + 3360 + 1024, 256, 0, stream>>>(
      points, outF, W1, Wa, Wb, feats, W1b, Wab, Wbb, featb, rdenomTab,
      cstage, knn, cidx, diffb, sums, cnt, stdp);
  gemm1_kernel<<<dim3(Mrows / 128, 3), 256, 0, stream>>>(featb, W1b, b1, knn, cidx,
                                                         diffb, stdp, rdenomTab, G1);
  gemm23_kernel<<<Mrows / 128, 512, 0, stream>>>(G1, Wab, ba, Wbb, bb, outF + Bn * Gn * 3);
}